// Round 20
// baseline (2080.773 us; speedup 1.0000x reference)
//
#include <hip/hip_runtime.h>
#include <hip/hip_bf16.h>
#include <math.h>

#define SEQ   1024
#define BATCH 256
#define IND   256
#define HID   256
#define NGATE 4

// ws layout:
//   wb    : bf16 [2 parts][4 gates][256 j][256 k], swizzled rows (1 MiB) @ 0
//           PRESCALED: gates f,i,o by -log2(e); gate g by -2*log2(e)
//   hr    : AGENT ring [2 slots][16 g][16 J] x 512B regions (256 KiB) @ 1 MiB
//   hfast : FAST ring, same layout — plain stores (XCD-local L2)     @ 1.25 MiB
// word(b,j4) = 4 bf16 {h[b][16J+j4..+3]}, elem-0 LSB = step stamp;
// single writer per region; stamps police staleness on BOTH rings.
#define WB_BYTES   (2 * NGATE * HID * 256 * 2)
#define HR_BYTES   (2 * 16 * 16 * 512)
#define REG_BYTES  512

#define SCALE_SIG  (-1.4426950408889634f)   // -log2(e)
#define SCALE_TANH (-2.8853900817779268f)   // -2*log2(e)

typedef float  f32x4  __attribute__((ext_vector_type(4)));
typedef short  bf16x8 __attribute__((ext_vector_type(8)));
typedef unsigned long long u64;

__device__ __forceinline__ short f2bf(float x) {
    __hip_bfloat16 h = __float2bfloat16(x);
    return *reinterpret_cast<short*>(&h);
}

__device__ __forceinline__ bf16x8 pack8(const float4& a, const float4& b) {
    union { short sh[8]; bf16x8 v; } u;
    u.sh[0] = f2bf(a.x); u.sh[1] = f2bf(a.y); u.sh[2] = f2bf(a.z); u.sh[3] = f2bf(a.w);
    u.sh[4] = f2bf(b.x); u.sh[5] = f2bf(b.y); u.sh[6] = f2bf(b.z); u.sh[7] = f2bf(b.w);
    return u.v;
}

__device__ __forceinline__ void gload_lds16(const void* g, void* l) {
    __builtin_amdgcn_global_load_lds(
        (const __attribute__((address_space(1))) unsigned int*)g,
        (__attribute__((address_space(3))) unsigned int*)l, 16, 0, 0);
}

__device__ __forceinline__ float gate_core(float zp) {
    return __builtin_amdgcn_rcpf(1.f + __builtin_amdgcn_exp2f(zp));
}

__device__ __forceinline__ bool stamp_ok(u64 q0, u64 q1, u64 ee) {
    return ((((q0 ^ ee) | (q1 ^ ee)) & 1ULL) == 0ULL);
}

// ---------------- prep kernels ----------------

__global__ __launch_bounds__(256) void prep_w(
    const float* __restrict__ Wf, const float* __restrict__ Wi,
    const float* __restrict__ Wg, const float* __restrict__ Wo,
    unsigned char* __restrict__ wb)
{
    int chunk = blockIdx.x * 256 + threadIdx.x;   // 65536 chunks of 8 floats
    int g  = chunk >> 14;
    int jj = (chunk >> 6) & 255;
    int k0 = (chunk & 63) * 8;
    int p  = k0 >> 8;
    int kk = k0 & 255;
    const float* W = (g == 0) ? Wf : (g == 1) ? Wi : (g == 2) ? Wg : Wo;
    const float sc = (g == 2) ? SCALE_TANH : SCALE_SIG;
    const float* src = W + (size_t)jj * 512 + k0;
    float4 a = *reinterpret_cast<const float4*>(src);
    float4 b = *reinterpret_cast<const float4*>(src + 4);
    a.x *= sc; a.y *= sc; a.z *= sc; a.w *= sc;
    b.x *= sc; b.y *= sc; b.z *= sc; b.w *= sc;
    size_t dstrow = (size_t)((p * 4 + g) * 256 + jj);
    *reinterpret_cast<bf16x8*>(
        wb + dstrow * 512 + ((kk * 2) ^ ((jj & 7) << 4))) = pack8(a, b);
}

// seed BOTH rings, both slots, stamp bit 1 (slot0 = h0 accepted at s=0;
// slot1 dummy rejected until t=0 overwrites). Poison 0xAA has LSB 0.
__global__ __launch_bounds__(256) void prep_h0(
    const float* __restrict__ h0, unsigned char* __restrict__ hr,
    unsigned char* __restrict__ hfast)
{
    int idx  = blockIdx.x * 256 + threadIdx.x;    // 32768 chunks of 8 B
    int slot = idx >> 14;
    int g    = (idx >> 10) & 15;
    int J    = (idx >> 6) & 15;
    int c    = idx & 63;
    int br   = c >> 2;
    int j4   = (c & 3) * 4;
    const float* src = h0 + (size_t)(g * 16 + br) * HID + J * 16 + j4;
    unsigned short v[4];
    #pragma unroll
    for (int i = 0; i < 4; ++i)
        v[i] = (unsigned short)((unsigned short)f2bf(src[i]) | 1u);
    u64 q = (u64)v[0] | ((u64)v[1] << 16) | ((u64)v[2] << 32) | ((u64)v[3] << 48);
    size_t off = (size_t)((slot * 16 + g) * 16 + J) * REG_BYTES + c * 8;
    *reinterpret_cast<u64*>(hr + off)    = q;
    *reinterpret_cast<u64*>(hfast + off) = q;
}

// ---------------- persistent sequence kernel ----------------
// R19 structure + dual-ring handoff: producer stores stamped word to the FAST
// ring (plain -> XCD-local L2; peers of a group share an XCD under round-robin
// since peer blk ≡ g_ mod 8) then to the AGENT ring (device coherence point).
// Consumer probes the fast ring via nontemporal loads (no L1 allocate -> L2
// read, compiler-counted waitcnts); every 8th retry round falls back to
// agent-scope probes of the agent ring -> progress under ANY XCD placement.
__global__ __launch_bounds__(64, 1) void lstm_seq(
    const float* __restrict__ x,  const float* __restrict__ c0,
    const float* __restrict__ bf_, const float* __restrict__ bi_,
    const float* __restrict__ bg_, const float* __restrict__ bo_,
    const unsigned char* __restrict__ wb, unsigned char* __restrict__ hr,
    unsigned char* __restrict__ hfast,
    float* __restrict__ out, float* __restrict__ hx, float* __restrict__ cxg)
{
    extern __shared__ __align__(16) unsigned char smem[];   // 64 KiB, init only

    const int lane = threadIdx.x & 63;
    const int blk  = blockIdx.x;
    const int g_   = blk & 15;
    const int J    = blk >> 4;
    const int j0   = J * 16;
    const int b0   = g_ * 16;

    const int lrow = lane & 15;
    const int hi   = lane >> 4;
    const int b    = b0 + lrow;          // this lane's batch row (acc col)
    const int jv   = j0 + hi * 4;        // this lane's first j (acc row base)

    // ---- stage W tile (64 KiB) into LDS once
    #pragma unroll
    for (int i = 0; i < 64; ++i) {
        gload_lds16(wb + ((size_t)((i >> 3) * 256 + j0 + (i & 7) * 2)) * 512
                       + lane * 16,
                    smem + i * 1024);
    }
    // biases, prescaled to match the weights
    float bF[4], bI[4], bG[4], bO[4];
    {
        float4 t;
        t = *reinterpret_cast<const float4*>(bf_ + jv);
        bF[0] = t.x * SCALE_SIG;  bF[1] = t.y * SCALE_SIG;
        bF[2] = t.z * SCALE_SIG;  bF[3] = t.w * SCALE_SIG;
        t = *reinterpret_cast<const float4*>(bi_ + jv);
        bI[0] = t.x * SCALE_SIG;  bI[1] = t.y * SCALE_SIG;
        bI[2] = t.z * SCALE_SIG;  bI[3] = t.w * SCALE_SIG;
        t = *reinterpret_cast<const float4*>(bg_ + jv);
        bG[0] = t.x * SCALE_TANH; bG[1] = t.y * SCALE_TANH;
        bG[2] = t.z * SCALE_TANH; bG[3] = t.w * SCALE_TANH;
        t = *reinterpret_cast<const float4*>(bo_ + jv);
        bO[0] = t.x * SCALE_SIG;  bO[1] = t.y * SCALE_SIG;
        bO[2] = t.z * SCALE_SIG;  bO[3] = t.w * SCALE_SIG;
    }
    float4 cst = *reinterpret_cast<const float4*>(c0 + (size_t)b * HID + jv);
    __syncthreads();    // drains gload_lds

    // ---- ALL W fragments -> registers: wf[part][kc][gate] (256 VGPR)
    const int bswz = (lrow & 7) << 4;
    bf16x8 wf[2][8][4];
    #pragma unroll
    for (int p = 0; p < 2; ++p) {
        #pragma unroll
        for (int kc = 0; kc < 8; ++kc) {
            int wbyte = (kc * 64 + hi * 16) ^ bswz;
            #pragma unroll
            for (int gg = 0; gg < 4; ++gg)
                wf[p][kc][gg] = *reinterpret_cast<const bf16x8*>(
                    smem + p * 32768 + gg * 8192 + lrow * 512 + wbyte);
        }
    }
    // LDS unused from here on.

    // ---- x pipeline: xpk = packed x(s); xt = in-flight x(s+1)
    float4 xt0[8], xt1[8];
    bf16x8 xpk[8];
    {
        const float* xr = x + (size_t)b * IND;
        #pragma unroll
        for (int kc = 0; kc < 8; ++kc) {
            const float* p = xr + kc * 32 + hi * 8;
            xt0[kc] = *reinterpret_cast<const float4*>(p);
            xt1[kc] = *reinterpret_cast<const float4*>(p + 4);
        }
        #pragma unroll
        for (int kc = 0; kc < 8; ++kc) xpk[kc] = pack8(xt0[kc], xt1[kc]);
        const float* xr1 = x + ((size_t)BATCH + b) * IND;
        #pragma unroll
        for (int kc = 0; kc < 8; ++kc) {
            const float* p = xr1 + kc * 32 + hi * 8;
            xt0[kc] = *reinterpret_cast<const float4*>(p);
            xt1[kc] = *reinterpret_cast<const float4*>(p + 4);
        }
    }

    unsigned char* regc[2] = {
        hr + (size_t)((0 * 16 + g_) * 16) * REG_BYTES,
        hr + (size_t)((1 * 16 + g_) * 16) * REG_BYTES };
    unsigned char* fstc[2] = {
        hfast + (size_t)((0 * 16 + g_) * 16) * REG_BYTES,
        hfast + (size_t)((1 * 16 + g_) * 16) * REG_BYTES };
    unsigned char* regp[2] = { regc[0] + J * REG_BYTES, regc[1] + J * REG_BYTES };
    unsigned char* fstp[2] = { fstc[0] + J * REG_BYTES, fstc[1] + J * REG_BYTES };
    const int uoff = lrow * 32 + (hi & 1) * 16;   // consumer in-region offset

    float hvprev[4] = {0.f, 0.f, 0.f, 0.f};

    for (int s = 0; s < SEQ; ++s) {
        const u64 ee = (u64)(((unsigned)(s + 3) >> 1) & 1);
        const unsigned char* hsrc = regc[s & 1];   // agent ring (fallback)
        const unsigned char* fsrc = fstc[s & 1];   // fast ring (L2)

        // ---- initial sample: FAST-ring nontemporal loads (L2-served;
        //      latency hides under phase A; compiler-counted waitcnts)
        u64 hq0[8], hq1[8];
        #pragma unroll
        for (int kc = 0; kc < 8; ++kc) {
            const u64* p = reinterpret_cast<const u64*>(
                fsrc + (2 * kc + (hi >> 1)) * REG_BYTES + uoff);
            hq0[kc] = __builtin_nontemporal_load(p);
            hq1[kc] = __builtin_nontemporal_load(p + 1);
        }
        __builtin_amdgcn_sched_barrier(0);

        // ---- phase A: x-part MFMA, all operands in registers (swapped)
        f32x4 aF = {0.f, 0.f, 0.f, 0.f};
        f32x4 aI = {0.f, 0.f, 0.f, 0.f};
        f32x4 aG = {0.f, 0.f, 0.f, 0.f};
        f32x4 aO = {0.f, 0.f, 0.f, 0.f};
        #pragma unroll
        for (int kc = 0; kc < 8; ++kc) {
            aF = __builtin_amdgcn_mfma_f32_16x16x32_bf16(wf[0][kc][0], xpk[kc], aF, 0, 0, 0);
            aI = __builtin_amdgcn_mfma_f32_16x16x32_bf16(wf[0][kc][1], xpk[kc], aI, 0, 0, 0);
            aG = __builtin_amdgcn_mfma_f32_16x16x32_bf16(wf[0][kc][2], xpk[kc], aG, 0, 0, 0);
            aO = __builtin_amdgcn_mfma_f32_16x16x32_bf16(wf[0][kc][3], xpk[kc], aO, 0, 0, 0);
        }
        // pack x(s+1) (its loads landed a full step ago)
        #pragma unroll
        for (int kc = 0; kc < 8; ++kc) xpk[kc] = pack8(xt0[kc], xt1[kc]);
        __builtin_amdgcn_sched_barrier(0);

        // ---- wait kc 0-3 -> MFMA; then kc 4-7 -> MFMA (half-split arrival).
        //      Retry rounds: fast-ring nt loads; every 8th round = agent-ring
        //      probes (progress guaranteed under any XCD placement).
        #pragma unroll
        for (int half = 0; half < 2; ++half) {
            const int kb = half * 4;
            unsigned pend = 0;
            #pragma unroll
            for (int kc = 0; kc < 4; ++kc)
                if (!stamp_ok(hq0[kb + kc], hq1[kb + kc], ee)) pend |= (1u << kc);
            int round = 0;
            while (pend) {
                ++round;
                if ((round & 7) == 0) {
                    #pragma unroll
                    for (int kc = 0; kc < 4; ++kc) {
                        if (pend & (1u << kc)) {
                            const u64* p = reinterpret_cast<const u64*>(
                                hsrc + (2 * (kb + kc) + (hi >> 1)) * REG_BYTES + uoff);
                            hq0[kb + kc] = __hip_atomic_load(p,     __ATOMIC_RELAXED, __HIP_MEMORY_SCOPE_AGENT);
                            hq1[kb + kc] = __hip_atomic_load(p + 1, __ATOMIC_RELAXED, __HIP_MEMORY_SCOPE_AGENT);
                            if (stamp_ok(hq0[kb + kc], hq1[kb + kc], ee)) pend &= ~(1u << kc);
                        }
                    }
                } else {
                    #pragma unroll
                    for (int kc = 0; kc < 4; ++kc) {
                        if (pend & (1u << kc)) {
                            const u64* p = reinterpret_cast<const u64*>(
                                fsrc + (2 * (kb + kc) + (hi >> 1)) * REG_BYTES + uoff);
                            hq0[kb + kc] = __builtin_nontemporal_load(p);
                            hq1[kb + kc] = __builtin_nontemporal_load(p + 1);
                            if (stamp_ok(hq0[kb + kc], hq1[kb + kc], ee)) pend &= ~(1u << kc);
                        }
                    }
                }
            }
            #pragma unroll
            for (int kc = 0; kc < 4; ++kc) {
                union { u64 q[2]; bf16x8 v; } u;
                u.q[0] = hq0[kb + kc]; u.q[1] = hq1[kb + kc];
                aF = __builtin_amdgcn_mfma_f32_16x16x32_bf16(wf[1][kb + kc][0], u.v, aF, 0, 0, 0);
                aI = __builtin_amdgcn_mfma_f32_16x16x32_bf16(wf[1][kb + kc][1], u.v, aI, 0, 0, 0);
                aG = __builtin_amdgcn_mfma_f32_16x16x32_bf16(wf[1][kb + kc][2], u.v, aG, 0, 0, 0);
                aO = __builtin_amdgcn_mfma_f32_16x16x32_bf16(wf[1][kb + kc][3], u.v, aO, 0, 0, 0);
            }
        }
        __builtin_amdgcn_sched_barrier(0);

        // ---- no-pollution window: deferred out[s-1] store + x(s+2) prefetch
        if (s > 0) {
            float4 ov = { hvprev[0], hvprev[1], hvprev[2], hvprev[3] };
            *reinterpret_cast<float4*>(
                out + (size_t)(s - 1) * (BATCH * HID) + (size_t)b * HID + jv) = ov;
        }
        if (s + 2 < SEQ) {
            const float* xr = x + ((size_t)(s + 2) * BATCH + b) * IND;
            #pragma unroll
            for (int kc = 0; kc < 8; ++kc) {
                const float* p = xr + kc * 32 + hi * 8;
                xt0[kc] = *reinterpret_cast<const float4*>(p);
                xt1[kc] = *reinterpret_cast<const float4*>(p + 4);
            }
        }
        __builtin_amdgcn_sched_barrier(0);

        // ---- epilogue: rcp/exp2 gates (prescaled z), no IEEE division
        float hv[4];
        #pragma unroll
        for (int r = 0; r < 4; ++r) {
            float fg = gate_core(aF[r] + bF[r]);              // sigmoid
            float ig = gate_core(aI[r] + bI[r]);              // sigmoid
            float gg = 2.f * gate_core(aG[r] + bG[r]) - 1.f;  // tanh
            float og = gate_core(aO[r] + bO[r]);              // sigmoid
            float c  = fg * ((const float*)&cst)[r] + ig * gg;
            ((float*)&cst)[r] = c;
            float tc = 2.f * gate_core(c * SCALE_TANH) - 1.f; // tanh(c)
            hv[r] = og * tc;
        }

        // ---- stamped 8B word: FAST ring first (local L2), then agent ring
        {
            u64 wv = (u64)(unsigned short)f2bf(hv[0])
                   | ((u64)(unsigned short)f2bf(hv[1]) << 16)
                   | ((u64)(unsigned short)f2bf(hv[2]) << 32)
                   | ((u64)(unsigned short)f2bf(hv[3]) << 48);
            wv = (wv & ~1ULL) | (u64)((s >> 1) & 1);
            *reinterpret_cast<volatile u64*>(fstp[(s + 1) & 1] + lrow * 32 + hi * 8) = wv;
            __hip_atomic_store(
                reinterpret_cast<u64*>(regp[(s + 1) & 1] + lrow * 32 + hi * 8),
                wv, __ATOMIC_RELAXED, __HIP_MEMORY_SCOPE_AGENT);
        }
        #pragma unroll
        for (int r = 0; r < 4; ++r) hvprev[r] = hv[r];

        if (s == SEQ - 1) {
            float4 ov = { hv[0], hv[1], hv[2], hv[3] };
            *reinterpret_cast<float4*>(
                out + (size_t)s * (BATCH * HID) + (size_t)b * HID + jv) = ov;
            *reinterpret_cast<float4*>(hx  + (size_t)b * HID + jv) = ov;
            *reinterpret_cast<float4*>(cxg + (size_t)b * HID + jv) = cst;
        }
    }
}

extern "C" void kernel_launch(void* const* d_in, const int* in_sizes, int n_in,
                              void* d_out, int out_size, void* d_ws, size_t ws_size,
                              hipStream_t stream) {
    const float* x  = (const float*)d_in[0];
    const float* h0 = (const float*)d_in[1];
    const float* c0 = (const float*)d_in[2];
    const float* Wf = (const float*)d_in[3];
    const float* bf = (const float*)d_in[4];
    const float* Wi = (const float*)d_in[5];
    const float* bi = (const float*)d_in[6];
    const float* Wg = (const float*)d_in[7];
    const float* bg = (const float*)d_in[8];
    const float* Wo = (const float*)d_in[9];
    const float* bo = (const float*)d_in[10];

    float* out = (float*)d_out;
    float* hx  = out + (size_t)SEQ * BATCH * HID;
    float* cx  = hx + BATCH * HID;

    unsigned char* wb = (unsigned char*)d_ws;
    unsigned char* hr = wb + WB_BYTES;
    unsigned char* hf = hr + HR_BYTES;

    prep_w<<<256, 256, 0, stream>>>(Wf, Wi, Wg, Wo, wb);
    prep_h0<<<128, 256, 0, stream>>>(h0, hr, hf);
    lstm_seq<<<256, 64, 65536, stream>>>(x, c0, bf, bi, bg, bo,
                                         wb, hr, hf, out, hx, cx);
}

// Round 21
// 2014.276 us; speedup vs baseline: 1.0330x; 1.0330x over previous
//
#include <hip/hip_runtime.h>
#include <hip/hip_bf16.h>
#include <math.h>

#define SEQ   1024
#define BATCH 256
#define IND   256
#define HID   256
#define NGATE 4

// ws layout:
//   wb : bf16 [2 parts][4 gates][256 j][256 k], swizzled rows (1 MiB) @ 0
//        PRESCALED: gates f,i,o by -log2(e); gate g by -2*log2(e)
//   hr : ring [2 slots][16 g][16 J] regions of 512B: word(b,j4) = 4 bf16
//        {h[b][16J+j4..+3]}, elem-0 LSB = step stamp; single writer @ 1 MiB
#define WB_BYTES   (2 * NGATE * HID * 256 * 2)
#define REG_BYTES  512

#define SCALE_SIG  (-1.4426950408889634f)   // -log2(e)
#define SCALE_TANH (-2.8853900817779268f)   // -2*log2(e)

typedef float  f32x4  __attribute__((ext_vector_type(4)));
typedef short  bf16x8 __attribute__((ext_vector_type(8)));
typedef unsigned long long u64;

__device__ __forceinline__ short f2bf(float x) {
    __hip_bfloat16 h = __float2bfloat16(x);
    return *reinterpret_cast<short*>(&h);
}

__device__ __forceinline__ bf16x8 pack8(const float4& a, const float4& b) {
    union { short sh[8]; bf16x8 v; } u;
    u.sh[0] = f2bf(a.x); u.sh[1] = f2bf(a.y); u.sh[2] = f2bf(a.z); u.sh[3] = f2bf(a.w);
    u.sh[4] = f2bf(b.x); u.sh[5] = f2bf(b.y); u.sh[6] = f2bf(b.z); u.sh[7] = f2bf(b.w);
    return u.v;
}

__device__ __forceinline__ void gload_lds16(const void* g, void* l) {
    __builtin_amdgcn_global_load_lds(
        (const __attribute__((address_space(1))) unsigned int*)g,
        (__attribute__((address_space(3))) unsigned int*)l, 16, 0, 0);
}

// zp already includes the -log2e (or -2log2e) prescale:
// sigmoid(z) = rcp(1 + exp2(zp)); tanh(z) = 2*rcp(1 + exp2(zp)) - 1
__device__ __forceinline__ float gate_core(float zp) {
    return __builtin_amdgcn_rcpf(1.f + __builtin_amdgcn_exp2f(zp));
}

__device__ __forceinline__ bool stamp_ok(u64 q0, u64 q1, u64 ee) {
    return ((((q0 ^ ee) | (q1 ^ ee)) & 1ULL) == 0ULL);
}

// ---------------- prep kernels (identical to R16) ----------------

__global__ __launch_bounds__(256) void prep_w(
    const float* __restrict__ Wf, const float* __restrict__ Wi,
    const float* __restrict__ Wg, const float* __restrict__ Wo,
    unsigned char* __restrict__ wb)
{
    int chunk = blockIdx.x * 256 + threadIdx.x;   // 65536 chunks of 8 floats
    int g  = chunk >> 14;
    int jj = (chunk >> 6) & 255;
    int k0 = (chunk & 63) * 8;
    int p  = k0 >> 8;
    int kk = k0 & 255;
    const float* W = (g == 0) ? Wf : (g == 1) ? Wi : (g == 2) ? Wg : Wo;
    const float sc = (g == 2) ? SCALE_TANH : SCALE_SIG;
    const float* src = W + (size_t)jj * 512 + k0;
    float4 a = *reinterpret_cast<const float4*>(src);
    float4 b = *reinterpret_cast<const float4*>(src + 4);
    a.x *= sc; a.y *= sc; a.z *= sc; a.w *= sc;
    b.x *= sc; b.y *= sc; b.z *= sc; b.w *= sc;
    size_t dstrow = (size_t)((p * 4 + g) * 256 + jj);
    *reinterpret_cast<bf16x8*>(
        wb + dstrow * 512 + ((kk * 2) ^ ((jj & 7) << 4))) = pack8(a, b);
}

__global__ __launch_bounds__(256) void prep_h0(
    const float* __restrict__ h0, unsigned char* __restrict__ hr)
{
    int idx  = blockIdx.x * 256 + threadIdx.x;    // 32768 chunks of 8 B
    int slot = idx >> 14;
    int g    = (idx >> 10) & 15;
    int J    = (idx >> 6) & 15;
    int c    = idx & 63;
    int br   = c >> 2;
    int j4   = (c & 3) * 4;
    const float* src = h0 + (size_t)(g * 16 + br) * HID + J * 16 + j4;
    unsigned short v[4];
    #pragma unroll
    for (int i = 0; i < 4; ++i)
        v[i] = (unsigned short)((unsigned short)f2bf(src[i]) | 1u);
    u64 q = (u64)v[0] | ((u64)v[1] << 16) | ((u64)v[2] << 32) | ((u64)v[3] << 48);
    *reinterpret_cast<u64*>(
        hr + (size_t)((slot * 16 + g) * 16 + J) * REG_BYTES + c * 8) = q;
}

// ---------------- persistent sequence kernel ----------------
// R16 structure + deferred out[s-1] store in the no-pollution window.
// This is the converged configuration (best measured: 2015 us).
__global__ __launch_bounds__(64, 1) void lstm_seq(
    const float* __restrict__ x,  const float* __restrict__ c0,
    const float* __restrict__ bf_, const float* __restrict__ bi_,
    const float* __restrict__ bg_, const float* __restrict__ bo_,
    const unsigned char* __restrict__ wb, unsigned char* __restrict__ hr,
    float* __restrict__ out, float* __restrict__ hx, float* __restrict__ cxg)
{
    extern __shared__ __align__(16) unsigned char smem[];   // 64 KiB, init only

    const int lane = threadIdx.x & 63;
    const int blk  = blockIdx.x;
    const int g_   = blk & 15;
    const int J    = blk >> 4;
    const int j0   = J * 16;
    const int b0   = g_ * 16;

    const int lrow = lane & 15;
    const int hi   = lane >> 4;
    const int b    = b0 + lrow;          // this lane's batch row (acc col)
    const int jv   = j0 + hi * 4;        // this lane's first j (acc row base)

    // ---- stage W tile (64 KiB) into LDS once
    #pragma unroll
    for (int i = 0; i < 64; ++i) {
        gload_lds16(wb + ((size_t)((i >> 3) * 256 + j0 + (i & 7) * 2)) * 512
                       + lane * 16,
                    smem + i * 1024);
    }
    // biases, prescaled to match the weights
    float bF[4], bI[4], bG[4], bO[4];
    {
        float4 t;
        t = *reinterpret_cast<const float4*>(bf_ + jv);
        bF[0] = t.x * SCALE_SIG;  bF[1] = t.y * SCALE_SIG;
        bF[2] = t.z * SCALE_SIG;  bF[3] = t.w * SCALE_SIG;
        t = *reinterpret_cast<const float4*>(bi_ + jv);
        bI[0] = t.x * SCALE_SIG;  bI[1] = t.y * SCALE_SIG;
        bI[2] = t.z * SCALE_SIG;  bI[3] = t.w * SCALE_SIG;
        t = *reinterpret_cast<const float4*>(bg_ + jv);
        bG[0] = t.x * SCALE_TANH; bG[1] = t.y * SCALE_TANH;
        bG[2] = t.z * SCALE_TANH; bG[3] = t.w * SCALE_TANH;
        t = *reinterpret_cast<const float4*>(bo_ + jv);
        bO[0] = t.x * SCALE_SIG;  bO[1] = t.y * SCALE_SIG;
        bO[2] = t.z * SCALE_SIG;  bO[3] = t.w * SCALE_SIG;
    }
    float4 cst = *reinterpret_cast<const float4*>(c0 + (size_t)b * HID + jv);
    __syncthreads();    // drains gload_lds

    // ---- ALL W fragments -> registers: wf[part][kc][gate] (256 VGPR)
    const int bswz = (lrow & 7) << 4;
    bf16x8 wf[2][8][4];
    #pragma unroll
    for (int p = 0; p < 2; ++p) {
        #pragma unroll
        for (int kc = 0; kc < 8; ++kc) {
            int wbyte = (kc * 64 + hi * 16) ^ bswz;
            #pragma unroll
            for (int gg = 0; gg < 4; ++gg)
                wf[p][kc][gg] = *reinterpret_cast<const bf16x8*>(
                    smem + p * 32768 + gg * 8192 + lrow * 512 + wbyte);
        }
    }
    // LDS unused from here on.

    // ---- x pipeline: xpk = packed x(s); xt = in-flight x(s+1)
    float4 xt0[8], xt1[8];
    bf16x8 xpk[8];
    {
        const float* xr = x + (size_t)b * IND;
        #pragma unroll
        for (int kc = 0; kc < 8; ++kc) {
            const float* p = xr + kc * 32 + hi * 8;
            xt0[kc] = *reinterpret_cast<const float4*>(p);
            xt1[kc] = *reinterpret_cast<const float4*>(p + 4);
        }
        #pragma unroll
        for (int kc = 0; kc < 8; ++kc) xpk[kc] = pack8(xt0[kc], xt1[kc]);
        const float* xr1 = x + ((size_t)BATCH + b) * IND;
        #pragma unroll
        for (int kc = 0; kc < 8; ++kc) {
            const float* p = xr1 + kc * 32 + hi * 8;
            xt0[kc] = *reinterpret_cast<const float4*>(p);
            xt1[kc] = *reinterpret_cast<const float4*>(p + 4);
        }
    }

    unsigned char* regc[2] = {
        hr + (size_t)((0 * 16 + g_) * 16) * REG_BYTES,
        hr + (size_t)((1 * 16 + g_) * 16) * REG_BYTES };
    unsigned char* regp[2] = { regc[0] + J * REG_BYTES, regc[1] + J * REG_BYTES };
    const int uoff = lrow * 32 + (hi & 1) * 16;   // consumer in-region offset

    float hvprev[4] = {0.f, 0.f, 0.f, 0.f};

    for (int s = 0; s < SEQ; ++s) {
        const u64 ee = (u64)(((unsigned)(s + 3) >> 1) & 1);
        const unsigned char* hsrc = regc[s & 1];

        // ---- issue initial h(s-1) probes (latency hides under phase A)
        u64 hq0[8], hq1[8];
        #pragma unroll
        for (int kc = 0; kc < 8; ++kc) {
            const u64* p = reinterpret_cast<const u64*>(
                hsrc + (2 * kc + (hi >> 1)) * REG_BYTES + uoff);
            hq0[kc] = __hip_atomic_load(p,     __ATOMIC_RELAXED, __HIP_MEMORY_SCOPE_AGENT);
            hq1[kc] = __hip_atomic_load(p + 1, __ATOMIC_RELAXED, __HIP_MEMORY_SCOPE_AGENT);
        }
        __builtin_amdgcn_sched_barrier(0);

        // ---- phase A: x-part MFMA, all operands in registers (swapped)
        f32x4 aF = {0.f, 0.f, 0.f, 0.f};
        f32x4 aI = {0.f, 0.f, 0.f, 0.f};
        f32x4 aG = {0.f, 0.f, 0.f, 0.f};
        f32x4 aO = {0.f, 0.f, 0.f, 0.f};
        #pragma unroll
        for (int kc = 0; kc < 8; ++kc) {
            aF = __builtin_amdgcn_mfma_f32_16x16x32_bf16(wf[0][kc][0], xpk[kc], aF, 0, 0, 0);
            aI = __builtin_amdgcn_mfma_f32_16x16x32_bf16(wf[0][kc][1], xpk[kc], aI, 0, 0, 0);
            aG = __builtin_amdgcn_mfma_f32_16x16x32_bf16(wf[0][kc][2], xpk[kc], aG, 0, 0, 0);
            aO = __builtin_amdgcn_mfma_f32_16x16x32_bf16(wf[0][kc][3], xpk[kc], aO, 0, 0, 0);
        }
        // pack x(s+1) (its loads landed a full step ago)
        #pragma unroll
        for (int kc = 0; kc < 8; ++kc) xpk[kc] = pack8(xt0[kc], xt1[kc]);
        __builtin_amdgcn_sched_barrier(0);

        // ---- wait kc 0-3 -> MFMA; then kc 4-7 -> MFMA (half-split arrival).
        #pragma unroll
        for (int half = 0; half < 2; ++half) {
            const int kb = half * 4;
            unsigned pend = 0;
            #pragma unroll
            for (int kc = 0; kc < 4; ++kc)
                if (!stamp_ok(hq0[kb + kc], hq1[kb + kc], ee)) pend |= (1u << kc);
            while (pend) {
                #pragma unroll
                for (int kc = 0; kc < 4; ++kc) {
                    if (pend & (1u << kc)) {
                        const u64* p = reinterpret_cast<const u64*>(
                            hsrc + (2 * (kb + kc) + (hi >> 1)) * REG_BYTES + uoff);
                        hq0[kb + kc] = __hip_atomic_load(p,     __ATOMIC_RELAXED, __HIP_MEMORY_SCOPE_AGENT);
                        hq1[kb + kc] = __hip_atomic_load(p + 1, __ATOMIC_RELAXED, __HIP_MEMORY_SCOPE_AGENT);
                        if (stamp_ok(hq0[kb + kc], hq1[kb + kc], ee)) pend &= ~(1u << kc);
                    }
                }
            }
            #pragma unroll
            for (int kc = 0; kc < 4; ++kc) {
                union { u64 q[2]; bf16x8 v; } u;
                u.q[0] = hq0[kb + kc]; u.q[1] = hq1[kb + kc];
                aF = __builtin_amdgcn_mfma_f32_16x16x32_bf16(wf[1][kb + kc][0], u.v, aF, 0, 0, 0);
                aI = __builtin_amdgcn_mfma_f32_16x16x32_bf16(wf[1][kb + kc][1], u.v, aI, 0, 0, 0);
                aG = __builtin_amdgcn_mfma_f32_16x16x32_bf16(wf[1][kb + kc][2], u.v, aG, 0, 0, 0);
                aO = __builtin_amdgcn_mfma_f32_16x16x32_bf16(wf[1][kb + kc][3], u.v, aO, 0, 0, 0);
            }
        }
        __builtin_amdgcn_sched_barrier(0);

        // ---- no-pollution window: deferred out[s-1] store + x(s+2) prefetch
        //      (younger than all consumed probes; ~800 cy older than step
        //      s+1's probes -> their ACKs never pollute probe waitcnts)
        if (s > 0) {
            float4 ov = { hvprev[0], hvprev[1], hvprev[2], hvprev[3] };
            *reinterpret_cast<float4*>(
                out + (size_t)(s - 1) * (BATCH * HID) + (size_t)b * HID + jv) = ov;
        }
        if (s + 2 < SEQ) {
            const float* xr = x + ((size_t)(s + 2) * BATCH + b) * IND;
            #pragma unroll
            for (int kc = 0; kc < 8; ++kc) {
                const float* p = xr + kc * 32 + hi * 8;
                xt0[kc] = *reinterpret_cast<const float4*>(p);
                xt1[kc] = *reinterpret_cast<const float4*>(p + 4);
            }
        }
        __builtin_amdgcn_sched_barrier(0);

        // ---- epilogue: rcp/exp2 gates (prescaled z), no IEEE division
        float hv[4];
        #pragma unroll
        for (int r = 0; r < 4; ++r) {
            float fg = gate_core(aF[r] + bF[r]);              // sigmoid
            float ig = gate_core(aI[r] + bI[r]);              // sigmoid
            float gg = 2.f * gate_core(aG[r] + bG[r]) - 1.f;  // tanh
            float og = gate_core(aO[r] + bO[r]);              // sigmoid
            float c  = fg * ((const float*)&cst)[r] + ig * gg;
            ((float*)&cst)[r] = c;
            float tc = 2.f * gate_core(c * SCALE_TANH) - 1.f; // tanh(c)
            hv[r] = og * tc;
        }

        // ---- stamped 8B ring word straight from registers (chain-critical)
        {
            u64 wv = (u64)(unsigned short)f2bf(hv[0])
                   | ((u64)(unsigned short)f2bf(hv[1]) << 16)
                   | ((u64)(unsigned short)f2bf(hv[2]) << 32)
                   | ((u64)(unsigned short)f2bf(hv[3]) << 48);
            wv = (wv & ~1ULL) | (u64)((s >> 1) & 1);
            __hip_atomic_store(
                reinterpret_cast<u64*>(regp[(s + 1) & 1] + lrow * 32 + hi * 8),
                wv, __ATOMIC_RELAXED, __HIP_MEMORY_SCOPE_AGENT);
        }
        #pragma unroll
        for (int r = 0; r < 4; ++r) hvprev[r] = hv[r];

        if (s == SEQ - 1) {
            // flush out[SEQ-1] + final states directly
            float4 ov = { hv[0], hv[1], hv[2], hv[3] };
            *reinterpret_cast<float4*>(
                out + (size_t)s * (BATCH * HID) + (size_t)b * HID + jv) = ov;
            *reinterpret_cast<float4*>(hx  + (size_t)b * HID + jv) = ov;
            *reinterpret_cast<float4*>(cxg + (size_t)b * HID + jv) = cst;
        }
    }
}

extern "C" void kernel_launch(void* const* d_in, const int* in_sizes, int n_in,
                              void* d_out, int out_size, void* d_ws, size_t ws_size,
                              hipStream_t stream) {
    const float* x  = (const float*)d_in[0];
    const float* h0 = (const float*)d_in[1];
    const float* c0 = (const float*)d_in[2];
    const float* Wf = (const float*)d_in[3];
    const float* bf = (const float*)d_in[4];
    const float* Wi = (const float*)d_in[5];
    const float* bi = (const float*)d_in[6];
    const float* Wg = (const float*)d_in[7];
    const float* bg = (const float*)d_in[8];
    const float* Wo = (const float*)d_in[9];
    const float* bo = (const float*)d_in[10];

    float* out = (float*)d_out;
    float* hx  = out + (size_t)SEQ * BATCH * HID;
    float* cx  = hx + BATCH * HID;

    unsigned char* wb = (unsigned char*)d_ws;
    unsigned char* hr = wb + WB_BYTES;

    prep_w<<<256, 256, 0, stream>>>(Wf, Wi, Wg, Wo, wb);
    prep_h0<<<128, 256, 0, stream>>>(h0, hr);
    lstm_seq<<<256, 64, 65536, stream>>>(x, c0, bf, bi, bg, bo,
                                         wb, hr, out, hx, cx);
}